// Round 3
// baseline (259.014 us; speedup 1.0000x reference)
//
#include <hip/hip_runtime.h>

#define F 256
#define TWO_F 512
#define BM 128
#define BN 256
#define BK 64
#define ASTR 72   // sA row stride (elements): 144 B = 9*16 B -> +4 banks/row, kills write conflicts

typedef __attribute__((ext_vector_type(8))) short short8;
typedef __attribute__((ext_vector_type(4))) float float4v;

// ---------- bf16 helpers ----------
static __device__ __forceinline__ unsigned short f2bf(float f) {   // full RNE, epilogue/prep only
    unsigned u = __float_as_uint(f);
    u += 0x7FFFu + ((u >> 16) & 1u);
    return (unsigned short)(u >> 16);
}
// pack two floats -> two bf16 (round-half-up) in ONE v_perm + 2 adds
static __device__ __forceinline__ unsigned pack2(float lo, float hi) {
    unsigned a = __float_as_uint(lo) + 0x8000u;
    unsigned b = __float_as_uint(hi) + 0x8000u;
    return __builtin_amdgcn_perm(b, a, 0x07060302u);  // bytes: [a.2,a.3,b.2,b.3]
}
static __device__ __forceinline__ float blo(unsigned u) { return __uint_as_float(u << 16); }
static __device__ __forceinline__ float rawf(unsigned u) { return __uint_as_float(u); }

// ---------- kernel 1: W1 fp32 [256][512] -> Wb bf16 [n][k] ----------
__global__ void prep_w_kernel(const float* __restrict__ W1, unsigned short* __restrict__ Wb) {
    int i = blockIdx.x * blockDim.x + threadIdx.x;
    if (i >= TWO_F * F) return;
    int n = i >> 8;
    int k = i & 255;
    float v = W1[(n & 255) * TWO_F + ((n >> 8) << 8) + k];
    Wb[i] = f2bf(v);
}

// ---------- kernel 2: C[m][n] = sum_k h[m][k]*Wb[n][k]; n<256 half gets +b1; bf16 out ----------
__global__ __launch_bounds__(256) void gemm_kernel(
    const float* __restrict__ h, const unsigned short* __restrict__ Wb,
    const float* __restrict__ b1v, unsigned short* __restrict__ C, int M)
{
    __shared__ unsigned short sA[BM * ASTR];  // padded stride
    __shared__ unsigned short sB[BN * BK];    // natural (global_load_lds layout)

    const int tid  = threadIdx.x;
    const int lane = tid & 63;
    const int wid  = tid >> 6;          // 4 waves: 2m x 2n
    const int wm   = wid >> 1;
    const int wn   = wid & 1;
    const int bm   = blockIdx.x * BM;
    const int bn   = blockIdx.y * BN;   // 0 (A-half) or 256 (B-half)

    // A staging: thread t -> row t>>1, k-seg (t&1)*32; clamp OOB rows (results discarded)
    const int ar = tid >> 1;
    const int ak = (tid & 1) * 32;
    int arow = bm + ar; if (arow > M - 1) arow = M - 1;
    const float* hrow = h + (size_t)arow * F + ak;

    // B staging: wave covers 64 rows, 8 issues x 8 rows, 16B/lane
    const int brow0 = wid * 64;
    const int b_r   = lane >> 3;
    const int b_k   = (lane & 7) * 8;

    float4v acc[4][8];
    #pragma unroll
    for (int i = 0; i < 4; ++i)
        #pragma unroll
        for (int j = 0; j < 8; ++j) acc[i][j] = (float4v)(0.f);

    const int quad = lane >> 4;
    const int l15  = lane & 15;

    for (int k0 = 0; k0 < F; k0 += BK) {
        // --- B tile: async global -> LDS ---
        #pragma unroll
        for (int p = 0; p < 8; ++p) {
            int r = brow0 + p * 8;
            const unsigned short* gp = Wb + (size_t)(bn + r + b_r) * F + k0 + b_k;
            __builtin_amdgcn_global_load_lds(
                (const __attribute__((address_space(1))) unsigned int*)gp,
                (__attribute__((address_space(3))) unsigned int*)&sB[r * BK],
                16, 0, 0);
        }

        // --- A tile: fp32 -> bf16 via perm-pack -> LDS ---
        const float* p = hrow + k0;
        #pragma unroll
        for (int half = 0; half < 2; ++half) {
            float4 a0 = *(const float4*)(p + half * 16 + 0);
            float4 a1 = *(const float4*)(p + half * 16 + 4);
            float4 a2 = *(const float4*)(p + half * 16 + 8);
            float4 a3 = *(const float4*)(p + half * 16 + 12);
            uint4 q0, q1;
            q0.x = pack2(a0.x, a0.y); q0.y = pack2(a0.z, a0.w);
            q0.z = pack2(a1.x, a1.y); q0.w = pack2(a1.z, a1.w);
            q1.x = pack2(a2.x, a2.y); q1.y = pack2(a2.z, a2.w);
            q1.z = pack2(a3.x, a3.y); q1.w = pack2(a3.z, a3.w);
            *(uint4*)&sA[ar * ASTR + ak + half * 16 + 0] = q0;
            *(uint4*)&sA[ar * ASTR + ak + half * 16 + 8] = q1;
        }
        __syncthreads();

        // --- MFMA: 2 k-steps of 32 ---
        #pragma unroll
        for (int ks = 0; ks < 2; ++ks) {
            short8 afr[4], bfr[8];
            #pragma unroll
            for (int mt = 0; mt < 4; ++mt)
                afr[mt] = *(const short8*)&sA[(wm * 64 + mt * 16 + l15) * ASTR + ks * 32 + quad * 8];
            #pragma unroll
            for (int nt = 0; nt < 8; ++nt)
                bfr[nt] = *(const short8*)&sB[(wn * 128 + nt * 16 + l15) * BK + ks * 32 + quad * 8];
            #pragma unroll
            for (int mt = 0; mt < 4; ++mt)
                #pragma unroll
                for (int nt = 0; nt < 8; ++nt)
                    acc[mt][nt] = __builtin_amdgcn_mfma_f32_16x16x32_bf16(
                        afr[mt], bfr[nt], acc[mt][nt], 0, 0, 0);
        }
        __syncthreads();
    }

    // --- epilogue: fold b1 into A-half (bn==0 block is entirely n<256), bf16 store ---
    float bias[8];
    #pragma unroll
    for (int nt = 0; nt < 8; ++nt) {
        int n = bn + wn * 128 + nt * 16 + l15;
        bias[nt] = (n < F) ? b1v[n] : 0.f;
    }
    #pragma unroll
    for (int mt = 0; mt < 4; ++mt) {
        int gm0 = bm + wm * 64 + mt * 16 + quad * 4;
        #pragma unroll
        for (int r = 0; r < 4; ++r) {
            int gm = gm0 + r;
            if (gm < M) {
                unsigned short* cp = C + (size_t)gm * TWO_F + bn + wn * 128 + l15;
                #pragma unroll
                for (int nt = 0; nt < 8; ++nt)
                    cp[nt * 16] = f2bf(acc[mt][nt][r] + bias[nt]);
            }
        }
    }
}

// ---------- kernel 3: per-edge score, one edge per 32 lanes ----------
__global__ __launch_bounds__(256) void edge_kernel(
    const unsigned short* __restrict__ C,
    const int* __restrict__ src, const int* __restrict__ dst,
    const float* __restrict__ w2,
    const float* __restrict__ b2, float* __restrict__ out, int E)
{
    const int lane = threadIdx.x & 31;
    const int e = blockIdx.x * 8 + (threadIdx.x >> 5);
    if (e >= E) return;
    const int s = src[e];
    const int d = dst[e];

    uint4 av = *(const uint4*)(C + (size_t)s * TWO_F + lane * 8);       // A-half (bias folded)
    uint4 bv = *(const uint4*)(C + (size_t)d * TWO_F + F + lane * 8);   // B-half
    float4 w0 = *(const float4*)(w2 + lane * 8);
    float4 w1 = *(const float4*)(w2 + lane * 8 + 4);

    // lo elems: shift-unpack; hi elems: raw float add (junk low mantissa <= 0.78%, one-sided)
    float sum;
    sum  = w0.x * fmaxf(blo(av.x) + blo(bv.x), 0.f);
    sum += w0.y * fmaxf(rawf(av.x) + rawf(bv.x), 0.f);
    sum += w0.z * fmaxf(blo(av.y) + blo(bv.y), 0.f);
    sum += w0.w * fmaxf(rawf(av.y) + rawf(bv.y), 0.f);
    sum += w1.x * fmaxf(blo(av.z) + blo(bv.z), 0.f);
    sum += w1.y * fmaxf(rawf(av.z) + rawf(bv.z), 0.f);
    sum += w1.z * fmaxf(blo(av.w) + blo(bv.w), 0.f);
    sum += w1.w * fmaxf(rawf(av.w) + rawf(bv.w), 0.f);

    #pragma unroll
    for (int off = 16; off > 0; off >>= 1)
        sum += __shfl_down(sum, off, 32);

    if (lane == 0) out[e] = sum + b2[0];
}

extern "C" void kernel_launch(void* const* d_in, const int* in_sizes, int n_in,
                              void* d_out, int out_size, void* d_ws, size_t ws_size,
                              hipStream_t stream) {
    const float* h    = (const float*)d_in[0];
    const int*   src  = (const int*)d_in[1];
    const int*   dst  = (const int*)d_in[2];
    const float* W1_w = (const float*)d_in[3];
    const float* W1_b = (const float*)d_in[4];
    const float* W2_w = (const float*)d_in[5];
    const float* W2_b = (const float*)d_in[6];
    float* out = (float*)d_out;

    const int M = in_sizes[0] / F;   // 50000
    const int E = in_sizes[1];       // 800000

    // ws: [Wb bf16 256KB][pad to 512KB][C bf16 ~51.2MB]
    unsigned short* Wb = (unsigned short*)d_ws;
    unsigned short* C  = (unsigned short*)((char*)d_ws + 512 * 1024);

    prep_w_kernel<<<(TWO_F * F + 255) / 256, 256, 0, stream>>>(W1_w, Wb);

    dim3 ggrid((M + BM - 1) / BM, TWO_F / BN);
    gemm_kernel<<<ggrid, 256, 0, stream>>>(h, Wb, W1_b, C, M);

    edge_kernel<<<(E + 7) / 8, 256, 0, stream>>>(C, src, dst, W2_w, W2_b, out, E);
}

// Round 4
// 241.264 us; speedup vs baseline: 1.0736x; 1.0736x over previous
//
#include <hip/hip_runtime.h>

#define F 256
#define TWO_F 512
#define BM 128
#define BN 128
#define BK 64
#define ASTR 72   // sA row stride (elems): 144 B -> +4 banks/row, conflict-free staging + frag reads

typedef __attribute__((ext_vector_type(8))) short short8;
typedef __attribute__((ext_vector_type(4))) float float4v;

// ---------- bf16 helpers ----------
static __device__ __forceinline__ unsigned short f2bf(float f) {
    unsigned u = __float_as_uint(f);
    u += 0x7FFFu + ((u >> 16) & 1u);
    return (unsigned short)(u >> 16);
}
// pack two floats -> two bf16 (round-half-up) in 2 adds + 1 v_perm
static __device__ __forceinline__ unsigned pack2(float lo, float hi) {
    unsigned a = __float_as_uint(lo) + 0x8000u;
    unsigned b = __float_as_uint(hi) + 0x8000u;
    return __builtin_amdgcn_perm(b, a, 0x07060302u);
}
static __device__ __forceinline__ float blo(unsigned u) { return __uint_as_float(u << 16); }
static __device__ __forceinline__ float rawf(unsigned u) { return __uint_as_float(u); }

// ---------- kernel 1: W1 fp32 [256][512] -> Wb bf16 [n][k], k-block-swizzled ----------
// Row n, within each 64-elem k-block, element kin is stored at (kin + (n&7)*8) & 63.
// This makes the later stride-128B ds_read_b128 of sB hit 8 distinct bank groups (2-way, free).
__global__ void prep_w_kernel(const float* __restrict__ W1, unsigned short* __restrict__ Wb) {
    int i = blockIdx.x * blockDim.x + threadIdx.x;
    if (i >= TWO_F * F) return;
    int n = i >> 8;
    int k = i & 255;
    float v = W1[(n & 255) * TWO_F + ((n >> 8) << 8) + k];
    int kin_sw = ((k & 63) + (n & 7) * 8) & 63;
    Wb[n * F + (k & ~63) + kin_sw] = f2bf(v);
}

// ---------- kernel 2: C[m][n] = sum_k h[m][k]*Wb[n][k] (+b1 for n<256), bf16 out ----------
__global__ __launch_bounds__(256, 3) void gemm_kernel(
    const float* __restrict__ h, const unsigned short* __restrict__ Wb,
    const float* __restrict__ b1v, unsigned short* __restrict__ C, int M)
{
    __shared__ unsigned short sA[BM * ASTR];
    __shared__ unsigned short sB[BN * BK];

    // XCD-pairing decode: virtual grid 1568 = 49*8 x 4; same bx -> same (i&7) -> same XCD,
    // dispatched ~8 slots apart -> h tile L2 reuse across the 4 by-blocks.
    const int ib = blockIdx.x;
    const int r8 = ib & 7;
    const int q  = ib >> 3;
    const int by = q & 3;
    const int bx = (q >> 2) * 8 + r8;
    const int bm = bx * BM;
    if (bm >= M) return;
    const int bn = by * BN;

    const int tid  = threadIdx.x;
    const int lane = tid & 63;
    const int wid  = tid >> 6;
    const int wm   = wid >> 1;
    const int wn   = wid & 1;

    // A staging: thread t -> row t>>1, k-seg (t&1)*32; clamp OOB rows (stores guarded)
    const int ar = tid >> 1;
    const int ak = (tid & 1) * 32;
    int arow = bm + ar; if (arow > M - 1) arow = M - 1;
    const float* hrow = h + (size_t)arow * F + ak;

    // B staging: wave covers rows wid*32..+31, 4 issues x 8 rows, 16B/lane
    const int brow0 = wid * 32;
    const int b_r   = lane >> 3;
    const int b_k   = (lane & 7) * 8;

    float4v acc[4][4];
    #pragma unroll
    for (int i = 0; i < 4; ++i)
        #pragma unroll
        for (int j = 0; j < 4; ++j) acc[i][j] = (float4v)(0.f);

    const int quad = lane >> 4;
    const int l15  = lane & 15;
    const int ksw  = (l15 & 7) * 8;   // per-row k rotation (matches prep_w swizzle)

    for (int k0 = 0; k0 < F; k0 += BK) {
        // --- B tile: async global -> LDS (verbatim copy of swizzled rows) ---
        #pragma unroll
        for (int p = 0; p < 4; ++p) {
            int r = brow0 + p * 8;
            const unsigned short* gp = Wb + (size_t)(bn + r + b_r) * F + k0 + b_k;
            __builtin_amdgcn_global_load_lds(
                (const __attribute__((address_space(1))) unsigned int*)gp,
                (__attribute__((address_space(3))) unsigned int*)&sB[r * BK],
                16, 0, 0);
        }

        // --- A tile: fp32 -> bf16 perm-pack -> LDS (padded stride) ---
        const float* p = hrow + k0;
        #pragma unroll
        for (int half = 0; half < 2; ++half) {
            float4 a0 = *(const float4*)(p + half * 16 + 0);
            float4 a1 = *(const float4*)(p + half * 16 + 4);
            float4 a2 = *(const float4*)(p + half * 16 + 8);
            float4 a3 = *(const float4*)(p + half * 16 + 12);
            uint4 q0, q1;
            q0.x = pack2(a0.x, a0.y); q0.y = pack2(a0.z, a0.w);
            q0.z = pack2(a1.x, a1.y); q0.w = pack2(a1.z, a1.w);
            q1.x = pack2(a2.x, a2.y); q1.y = pack2(a2.z, a2.w);
            q1.z = pack2(a3.x, a3.y); q1.w = pack2(a3.z, a3.w);
            *(uint4*)&sA[ar * ASTR + ak + half * 16 + 0] = q0;
            *(uint4*)&sA[ar * ASTR + ak + half * 16 + 8] = q1;
        }
        __syncthreads();

        // --- MFMA: 2 k-steps of 32 ---
        #pragma unroll
        for (int ks = 0; ks < 2; ++ks) {
            short8 afr[4], bfr[4];
            #pragma unroll
            for (int mt = 0; mt < 4; ++mt)
                afr[mt] = *(const short8*)&sA[(wm * 64 + mt * 16 + l15) * ASTR + ks * 32 + quad * 8];
            #pragma unroll
            for (int nt = 0; nt < 4; ++nt) {
                int koff = (ks * 32 + quad * 8 + ksw) & 63;   // un-rotate the swizzle
                bfr[nt] = *(const short8*)&sB[(wn * 64 + nt * 16 + l15) * BK + koff];
            }
            #pragma unroll
            for (int mt = 0; mt < 4; ++mt)
                #pragma unroll
                for (int nt = 0; nt < 4; ++nt)
                    acc[mt][nt] = __builtin_amdgcn_mfma_f32_16x16x32_bf16(
                        afr[mt], bfr[nt], acc[mt][nt], 0, 0, 0);
        }
        __syncthreads();
    }

    // --- epilogue: +b1 for n<256 half, bf16 store ---
    float bias[4];
    #pragma unroll
    for (int nt = 0; nt < 4; ++nt) {
        int n = bn + wn * 64 + nt * 16 + l15;
        bias[nt] = (n < F) ? b1v[n] : 0.f;
    }
    #pragma unroll
    for (int mt = 0; mt < 4; ++mt) {
        int gm0 = bm + wm * 64 + mt * 16 + quad * 4;
        #pragma unroll
        for (int rr = 0; rr < 4; ++rr) {
            int gm = gm0 + rr;
            if (gm < M) {
                unsigned short* cp = C + (size_t)gm * TWO_F + bn + wn * 64 + l15;
                #pragma unroll
                for (int nt = 0; nt < 4; ++nt)
                    cp[nt * 16] = f2bf(acc[mt][nt][rr] + bias[nt]);
            }
        }
    }
}

// ---------- kernel 3: per-edge score, 2 edges per 32-lane group (4 gathers in flight) ----------
__global__ __launch_bounds__(256) void edge_kernel(
    const unsigned short* __restrict__ C,
    const int* __restrict__ src, const int* __restrict__ dst,
    const float* __restrict__ w2,
    const float* __restrict__ b2, float* __restrict__ out, int E)
{
    const int lane = threadIdx.x & 31;
    const int g = blockIdx.x * 8 + (threadIdx.x >> 5);
    const int e0 = g * 2;
    if (e0 >= E) return;
    const int s0 = src[e0], d0 = dst[e0];
    const int s1 = src[e0 + 1], d1 = dst[e0 + 1];

    uint4 av0 = *(const uint4*)(C + (size_t)s0 * TWO_F + lane * 8);
    uint4 bv0 = *(const uint4*)(C + (size_t)d0 * TWO_F + F + lane * 8);
    uint4 av1 = *(const uint4*)(C + (size_t)s1 * TWO_F + lane * 8);
    uint4 bv1 = *(const uint4*)(C + (size_t)d1 * TWO_F + F + lane * 8);
    float4 w0 = *(const float4*)(w2 + lane * 8);
    float4 w1 = *(const float4*)(w2 + lane * 8 + 4);

    float sum0, sum1;
    sum0  = w0.x * fmaxf(blo(av0.x) + blo(bv0.x), 0.f);
    sum0 += w0.y * fmaxf(rawf(av0.x) + rawf(bv0.x), 0.f);
    sum0 += w0.z * fmaxf(blo(av0.y) + blo(bv0.y), 0.f);
    sum0 += w0.w * fmaxf(rawf(av0.y) + rawf(bv0.y), 0.f);
    sum0 += w1.x * fmaxf(blo(av0.z) + blo(bv0.z), 0.f);
    sum0 += w1.y * fmaxf(rawf(av0.z) + rawf(bv0.z), 0.f);
    sum0 += w1.z * fmaxf(blo(av0.w) + blo(bv0.w), 0.f);
    sum0 += w1.w * fmaxf(rawf(av0.w) + rawf(bv0.w), 0.f);

    sum1  = w0.x * fmaxf(blo(av1.x) + blo(bv1.x), 0.f);
    sum1 += w0.y * fmaxf(rawf(av1.x) + rawf(bv1.x), 0.f);
    sum1 += w0.z * fmaxf(blo(av1.y) + blo(bv1.y), 0.f);
    sum1 += w0.w * fmaxf(rawf(av1.y) + rawf(bv1.y), 0.f);
    sum1 += w1.x * fmaxf(blo(av1.z) + blo(bv1.z), 0.f);
    sum1 += w1.y * fmaxf(rawf(av1.z) + rawf(bv1.z), 0.f);
    sum1 += w1.z * fmaxf(blo(av1.w) + blo(bv1.w), 0.f);
    sum1 += w1.w * fmaxf(rawf(av1.w) + rawf(bv1.w), 0.f);

    #pragma unroll
    for (int off = 16; off > 0; off >>= 1) {
        sum0 += __shfl_down(sum0, off, 32);
        sum1 += __shfl_down(sum1, off, 32);
    }

    if (lane == 0) {
        float b = b2[0];
        out[e0]     = sum0 + b;
        out[e0 + 1] = sum1 + b;
    }
}

extern "C" void kernel_launch(void* const* d_in, const int* in_sizes, int n_in,
                              void* d_out, int out_size, void* d_ws, size_t ws_size,
                              hipStream_t stream) {
    const float* h    = (const float*)d_in[0];
    const int*   src  = (const int*)d_in[1];
    const int*   dst  = (const int*)d_in[2];
    const float* W1_w = (const float*)d_in[3];
    const float* W1_b = (const float*)d_in[4];
    const float* W2_w = (const float*)d_in[5];
    const float* W2_b = (const float*)d_in[6];
    float* out = (float*)d_out;

    const int M = in_sizes[0] / F;   // 50000
    const int E = in_sizes[1];       // 800000

    // ws: [Wb bf16 256KB][pad to 512KB][C bf16 ~51.2MB]
    unsigned short* Wb = (unsigned short*)d_ws;
    unsigned short* C  = (unsigned short*)((char*)d_ws + 512 * 1024);

    prep_w_kernel<<<(TWO_F * F + 255) / 256, 256, 0, stream>>>(W1_w, Wb);

    // virtual grid: 49*8 bx-slots x 4 by, XCD-paired; bx >= 391 blocks self-eliminate
    int nbx = ((M + BM - 1) / BM + 7) / 8 * 8;     // 392
    gemm_kernel<<<nbx * 4, 256, 0, stream>>>(h, Wb, W1_b, C, M);

    edge_kernel<<<(E / 2 + 7) / 8, 256, 0, stream>>>(C, src, dst, W2_w, W2_b, out, E);
}

// Round 5
// 230.368 us; speedup vs baseline: 1.1243x; 1.0473x over previous
//
#include <hip/hip_runtime.h>

#define F 256
#define TWO_F 512
#define BM 128
#define BN 128
#define BK 64

typedef __attribute__((ext_vector_type(8))) short short8;
typedef __attribute__((ext_vector_type(4))) float float4v;

// ---------- bf16 helpers ----------
static __device__ __forceinline__ unsigned short f2bf(float f) {
    unsigned u = __float_as_uint(f);
    u += 0x7FFFu + ((u >> 16) & 1u);
    return (unsigned short)(u >> 16);
}
// pack two floats -> two bf16 (round-half-up) in 2 adds + 1 v_perm
static __device__ __forceinline__ unsigned pack2(float lo, float hi) {
    unsigned a = __float_as_uint(lo) + 0x8000u;
    unsigned b = __float_as_uint(hi) + 0x8000u;
    return __builtin_amdgcn_perm(b, a, 0x07060302u);
}
static __device__ __forceinline__ float blo(unsigned u) { return __uint_as_float(u << 16); }
static __device__ __forceinline__ float rawf(unsigned u) { return __uint_as_float(u); }

// ---------- kernel 1: W1 fp32 [256][512] -> Wb bf16 [n][k], 64-block k-rotated by (n&7)*8 ----------
__global__ void prep_w_kernel(const float* __restrict__ W1, unsigned short* __restrict__ Wb) {
    int i = blockIdx.x * blockDim.x + threadIdx.x;
    if (i >= TWO_F * F) return;
    int n = i >> 8;
    int k = i & 255;
    float v = W1[(n & 255) * TWO_F + ((n >> 8) << 8) + k];
    int kin_sw = ((k & 63) + (n & 7) * 8) & 63;
    Wb[n * F + (k & ~63) + kin_sw] = f2bf(v);
}

// ---------- kernel 2: h fp32 [M][256] -> hb bf16 [M][256], same 64-block rotation by (m&7)*8 ----------
__global__ __launch_bounds__(256) void prep_h_kernel(
    const float* __restrict__ h, unsigned short* __restrict__ hb, int M)
{
    int i = blockIdx.x * blockDim.x + threadIdx.x;   // pair index
    if (i >= M * 128) return;
    int m = i >> 7;
    int kp = (i & 127) * 2;
    float2 v = *(const float2*)(h + (size_t)m * F + kp);
    unsigned pk = pack2(v.x, v.y);
    int ksw = ((kp & 63) + (m & 7) * 8) & 63;        // rotation is multiple of 8 -> pair stays intact
    *(unsigned*)(hb + (size_t)m * F + (kp & ~63) + ksw) = pk;
}

// ---------- kernel 3: C[m][n] = sum_k hb[m][k]*Wb[n][k] (+b1 for n<256), bf16 out ----------
// Both operands staged via global_load_lds (16B); swizzle makes frag ds_read_b128 conflict-free.
__global__ __launch_bounds__(256, 3) void gemm_kernel(
    const unsigned short* __restrict__ hb, const unsigned short* __restrict__ Wb,
    const float* __restrict__ b1v, unsigned short* __restrict__ C, int M)
{
    __shared__ unsigned short sA[BM * BK];
    __shared__ unsigned short sB[BN * BK];

    // XCD-pairing decode: same bx -> same (ib&7) slot -> same XCD; 4 by-blocks reuse the h tile in L2.
    const int ib = blockIdx.x;
    const int r8 = ib & 7;
    const int q  = ib >> 3;
    const int by = q & 3;
    const int bx = (q >> 2) * 8 + r8;
    const int bm = bx * BM;
    if (bm >= M) return;
    const int bn = by * BN;

    const int tid  = threadIdx.x;
    const int lane = tid & 63;
    const int wid  = tid >> 6;
    const int wm   = wid >> 1;
    const int wn   = wid & 1;

    // staging: wave covers rows wid*32..+31 of each tile, 4 issues x 8 rows, 16B/lane
    const int row0 = wid * 32;
    const int st_r = lane >> 3;
    const int st_k = (lane & 7) * 8;

    float4v acc[4][4];
    #pragma unroll
    for (int i = 0; i < 4; ++i)
        #pragma unroll
        for (int j = 0; j < 4; ++j) acc[i][j] = (float4v)(0.f);

    const int quad = lane >> 4;
    const int l15  = lane & 15;
    const int rot  = (l15 & 7) * 8;   // un-rotation for frag reads (row&7 == l15&7)

    for (int k0 = 0; k0 < F; k0 += BK) {
        #pragma unroll
        for (int p = 0; p < 4; ++p) {
            int r = row0 + p * 8;
            int am = bm + r + st_r; if (am > M - 1) am = M - 1;   // clamp; results discarded
            const unsigned short* ga = hb + (size_t)am * F + k0 + st_k;
            __builtin_amdgcn_global_load_lds(
                (const __attribute__((address_space(1))) unsigned int*)ga,
                (__attribute__((address_space(3))) unsigned int*)&sA[r * BK],
                16, 0, 0);
            const unsigned short* gb = Wb + (size_t)(bn + r + st_r) * F + k0 + st_k;
            __builtin_amdgcn_global_load_lds(
                (const __attribute__((address_space(1))) unsigned int*)gb,
                (__attribute__((address_space(3))) unsigned int*)&sB[r * BK],
                16, 0, 0);
        }
        __syncthreads();

        #pragma unroll
        for (int ks = 0; ks < 2; ++ks) {
            const int koff = (ks * 32 + quad * 8 + rot) & 63;
            short8 afr[4], bfr[4];
            #pragma unroll
            for (int mt = 0; mt < 4; ++mt)
                afr[mt] = *(const short8*)&sA[(wm * 64 + mt * 16 + l15) * BK + koff];
            #pragma unroll
            for (int nt = 0; nt < 4; ++nt)
                bfr[nt] = *(const short8*)&sB[(wn * 64 + nt * 16 + l15) * BK + koff];
            #pragma unroll
            for (int mt = 0; mt < 4; ++mt)
                #pragma unroll
                for (int nt = 0; nt < 4; ++nt)
                    acc[mt][nt] = __builtin_amdgcn_mfma_f32_16x16x32_bf16(
                        afr[mt], bfr[nt], acc[mt][nt], 0, 0, 0);
        }
        __syncthreads();
    }

    // epilogue: +b1 for the n<256 half, bf16 store
    float bias[4];
    #pragma unroll
    for (int nt = 0; nt < 4; ++nt) {
        int n = bn + wn * 64 + nt * 16 + l15;
        bias[nt] = (n < F) ? b1v[n] : 0.f;
    }
    #pragma unroll
    for (int mt = 0; mt < 4; ++mt) {
        int gm0 = bm + wm * 64 + mt * 16 + quad * 4;
        #pragma unroll
        for (int rr = 0; rr < 4; ++rr) {
            int gm = gm0 + rr;
            if (gm < M) {
                unsigned short* cp = C + (size_t)gm * TWO_F + bn + wn * 64 + l15;
                #pragma unroll
                for (int nt = 0; nt < 4; ++nt)
                    cp[nt * 16] = f2bf(acc[mt][nt][rr] + bias[nt]);
            }
        }
    }
}

// ---------- kernel 4: per-edge score, 4 edges per 32-lane group (8 gathers in flight) ----------
__global__ __launch_bounds__(256) void edge_kernel(
    const unsigned short* __restrict__ C,
    const int* __restrict__ src, const int* __restrict__ dst,
    const float* __restrict__ w2,
    const float* __restrict__ b2, float* __restrict__ out, int E)
{
    const int lane = threadIdx.x & 31;
    const int g = blockIdx.x * 8 + (threadIdx.x >> 5);
    const int e0 = g * 4;
    if (e0 >= E) return;
    int4 sv = *(const int4*)(src + e0);
    int4 dv = *(const int4*)(dst + e0);

    const unsigned short* Ca = C + lane * 8;
    const unsigned short* Cb = C + F + lane * 8;
    uint4 a0 = *(const uint4*)(Ca + (size_t)sv.x * TWO_F);
    uint4 b0 = *(const uint4*)(Cb + (size_t)dv.x * TWO_F);
    uint4 a1 = *(const uint4*)(Ca + (size_t)sv.y * TWO_F);
    uint4 b1 = *(const uint4*)(Cb + (size_t)dv.y * TWO_F);
    uint4 a2 = *(const uint4*)(Ca + (size_t)sv.z * TWO_F);
    uint4 b2v = *(const uint4*)(Cb + (size_t)dv.z * TWO_F);
    uint4 a3 = *(const uint4*)(Ca + (size_t)sv.w * TWO_F);
    uint4 b3 = *(const uint4*)(Cb + (size_t)dv.w * TWO_F);
    float4 w0 = *(const float4*)(w2 + lane * 8);
    float4 w1 = *(const float4*)(w2 + lane * 8 + 4);

#define ESUM(s, av, bv)                                   \
    s  = w0.x * fmaxf(blo(av.x) + blo(bv.x), 0.f);        \
    s += w0.y * fmaxf(rawf(av.x) + rawf(bv.x), 0.f);      \
    s += w0.z * fmaxf(blo(av.y) + blo(bv.y), 0.f);        \
    s += w0.w * fmaxf(rawf(av.y) + rawf(bv.y), 0.f);      \
    s += w1.x * fmaxf(blo(av.z) + blo(bv.z), 0.f);        \
    s += w1.y * fmaxf(rawf(av.z) + rawf(bv.z), 0.f);      \
    s += w1.z * fmaxf(blo(av.w) + blo(bv.w), 0.f);        \
    s += w1.w * fmaxf(rawf(av.w) + rawf(bv.w), 0.f);

    float sum0, sum1, sum2, sum3;
    ESUM(sum0, a0, b0)
    ESUM(sum1, a1, b1)
    ESUM(sum2, a2, b2v)
    ESUM(sum3, a3, b3)
#undef ESUM

    #pragma unroll
    for (int off = 16; off > 0; off >>= 1) {
        sum0 += __shfl_down(sum0, off, 32);
        sum1 += __shfl_down(sum1, off, 32);
        sum2 += __shfl_down(sum2, off, 32);
        sum3 += __shfl_down(sum3, off, 32);
    }

    if (lane == 0) {
        float b = b2[0];
        *(float4*)(out + e0) = make_float4(sum0 + b, sum1 + b, sum2 + b, sum3 + b);
    }
}

extern "C" void kernel_launch(void* const* d_in, const int* in_sizes, int n_in,
                              void* d_out, int out_size, void* d_ws, size_t ws_size,
                              hipStream_t stream) {
    const float* h    = (const float*)d_in[0];
    const int*   src  = (const int*)d_in[1];
    const int*   dst  = (const int*)d_in[2];
    const float* W1_w = (const float*)d_in[3];
    const float* W1_b = (const float*)d_in[4];
    const float* W2_w = (const float*)d_in[5];
    const float* W2_b = (const float*)d_in[6];
    float* out = (float*)d_out;

    const int M = in_sizes[0] / F;   // 50000
    const int E = in_sizes[1];       // 800000

    // ws: [Wb bf16 256KB][pad to 512KB][hb bf16 25.6MB, pad to 26MB][C bf16 51.2MB]
    unsigned short* Wb = (unsigned short*)d_ws;
    unsigned short* hb = (unsigned short*)((char*)d_ws + 512 * 1024);
    unsigned short* C  = (unsigned short*)((char*)d_ws + 512 * 1024 + 26 * 1024 * 1024);

    prep_w_kernel<<<(TWO_F * F + 255) / 256, 256, 0, stream>>>(W1_w, Wb);
    prep_h_kernel<<<(M * 128 + 255) / 256, 256, 0, stream>>>(h, hb, M);

    int nbx = ((M + BM - 1) / BM + 7) / 8 * 8;     // 392
    gemm_kernel<<<nbx * 4, 256, 0, stream>>>(hb, Wb, W1_b, C, M);

    edge_kernel<<<(E / 4 + 7) / 8, 256, 0, stream>>>(C, src, dst, W2_w, W2_b, out, E);
}